// Round 7
// baseline (251.123 us; speedup 1.0000x reference)
//
#include <hip/hip_runtime.h>
#include <float.h>

#define NUM_Q 8192
#define NUM_P 4096
#define ROWS  4              // rows per block (pipelined)
#define VEC   (NUM_P / 4)    // 1024 f32x4 per row

typedef float  f32x4 __attribute__((ext_vector_type(4)));
typedef int    i32x4 __attribute__((ext_vector_type(4)));

__device__ __forceinline__ unsigned mask_of(const i32x4* yv) {
    unsigned m = 0u;
#pragma unroll
    for (int i = 0; i < 4; ++i) {
        m |= ((unsigned)(yv[i].x == 1)     ) << (4 * i);
        m |= ((unsigned)(yv[i].y == 1) << 1) << (4 * i);
        m |= ((unsigned)(yv[i].z == 1) << 2) << (4 * i);
        m |= ((unsigned)(yv[i].w == 1) << 3) << (4 * i);
    }
    return m;
}

// Persistent pipelined block: 4 waves, 4 adjacent rows per block.
// Row r+1's 8 NT loads are issued BEFORE row r's reduction and stay in
// flight across a RAW s_barrier (ds-visibility via lgkmcnt(0) only — no
// compiler vmcnt(0) drain, unlike __syncthreads). Per-wave hinge partials
// go straight to ws[row*4+wave]; parity-double-buffered smin needs only
// one barrier per row.
__global__ __launch_bounds__(256)
void mmrl_kernel(const float* __restrict__ pred,
                 const int* __restrict__ y,
                 float* __restrict__ ws) {
    const int t    = threadIdx.x;
    const int wave = t >> 6;
    const int lane = t & 63;
    const int row0 = blockIdx.x * ROWS;

    const f32x4* P = reinterpret_cast<const f32x4*>(pred) + (size_t)row0 * VEC;
    const i32x4* Y = reinterpret_cast<const i32x4*>(y)    + (size_t)row0 * VEC;

    __shared__ float smin[2][4];

    i32x4 yv[4];
    f32x4 pv[4], nv[4];

    // ---- prologue: row 0 ----
#pragma unroll
    for (int i = 0; i < 4; ++i) yv[i] = __builtin_nontemporal_load(&Y[t + 256 * i]);
#pragma unroll
    for (int i = 0; i < 4; ++i) pv[i] = __builtin_nontemporal_load(&P[t + 256 * i]);
    unsigned m = mask_of(yv);

#pragma unroll
    for (int r = 0; r < ROWS; ++r) {
        // ---- issue row r+1's loads; they remain in flight across the barrier ----
        if (r + 1 < ROWS) {
            const size_t base = (size_t)(r + 1) * VEC + t;
#pragma unroll
            for (int i = 0; i < 4; ++i) yv[i] = __builtin_nontemporal_load(&Y[base + 256 * i]);
#pragma unroll
            for (int i = 0; i < 4; ++i) nv[i] = __builtin_nontemporal_load(&P[base + 256 * i]);
        }

        // ---- phase 1: masked min on current row ----
        float lmin = FLT_MAX;
#pragma unroll
        for (int i = 0; i < 4; ++i) {
            lmin = fminf(lmin, (m & (1u << (4 * i))) ? pv[i].x : FLT_MAX);
            lmin = fminf(lmin, (m & (2u << (4 * i))) ? pv[i].y : FLT_MAX);
            lmin = fminf(lmin, (m & (4u << (4 * i))) ? pv[i].z : FLT_MAX);
            lmin = fminf(lmin, (m & (8u << (4 * i))) ? pv[i].w : FLT_MAX);
        }
#pragma unroll
        for (int off = 32; off > 0; off >>= 1)
            lmin = fminf(lmin, __shfl_xor(lmin, off));

        if (lane == 0) smin[r & 1][wave] = lmin;
        // LDS write visible to the workgroup, then RAW barrier: global NT
        // loads (vmcnt) intentionally NOT drained here.
        asm volatile("s_waitcnt lgkmcnt(0)" ::: "memory");
        __builtin_amdgcn_s_barrier();
        const float rmin = fminf(fminf(smin[r & 1][0], smin[r & 1][1]),
                                 fminf(smin[r & 1][2], smin[r & 1][3]));

        // ---- phase 2: hinge sum; per-wave partial straight to ws ----
        float lsum = 0.0f;
#pragma unroll
        for (int i = 0; i < 4; ++i) {
            lsum += (m & (1u << (4 * i))) ? 0.0f : fmaxf(pv[i].x - rmin, 0.0f);
            lsum += (m & (2u << (4 * i))) ? 0.0f : fmaxf(pv[i].y - rmin, 0.0f);
            lsum += (m & (4u << (4 * i))) ? 0.0f : fmaxf(pv[i].z - rmin, 0.0f);
            lsum += (m & (8u << (4 * i))) ? 0.0f : fmaxf(pv[i].w - rmin, 0.0f);
        }
#pragma unroll
        for (int off = 32; off > 0; off >>= 1)
            lsum += __shfl_xor(lsum, off);

        if (lane == 0) ws[(size_t)(row0 + r) * 4 + wave] = lsum;

        // ---- advance pipeline (first use of row r+1 data -> vmcnt wait here) ----
        if (r + 1 < ROWS) {
            m = mask_of(yv);
#pragma unroll
            for (int i = 0; i < 4; ++i) pv[i] = nv[i];
        }
    }
}

// Single-block reduction over 8192 rows x 4 wave-partials = 32768 floats.
__global__ __launch_bounds__(256)
void mmrl_reduce_kernel(const float* __restrict__ partial,
                        float* __restrict__ out) {
    const int t = threadIdx.x;
    const f32x4* p4 = reinterpret_cast<const f32x4*>(partial);
    float s = 0.0f;
#pragma unroll
    for (int i = 0; i < 32; ++i) {  // 256 threads * 32 f32x4 = 32768 floats
        f32x4 v = p4[t + 256 * i];
        s += (v.x + v.y) + (v.z + v.w);
    }
#pragma unroll
    for (int off = 32; off > 0; off >>= 1)
        s += __shfl_xor(s, off);

    __shared__ float ss[4];
    if ((t & 63) == 0) ss[t >> 6] = s;
    __syncthreads();

    if (t == 0) {
        const float total = (ss[0] + ss[1]) + (ss[2] + ss[3]);
        // mean over Q*P = 2^25 — exact power-of-two scale
        out[0] = total * (1.0f / ((float)NUM_Q * (float)NUM_P));
    }
}

extern "C" void kernel_launch(void* const* d_in, const int* in_sizes, int n_in,
                              void* d_out, int out_size, void* d_ws, size_t ws_size,
                              hipStream_t stream) {
    const float* pred = (const float*)d_in[0];
    const int*   y    = (const int*)d_in[1];
    float* out = (float*)d_out;
    float* ws  = (float*)d_ws;  // 32768 floats = 128 KB scratch

    mmrl_kernel<<<NUM_Q / ROWS, 256, 0, stream>>>(pred, y, ws);
    mmrl_reduce_kernel<<<1, 256, 0, stream>>>(ws, out);
}